// Round 12
// baseline (233.655 us; speedup 1.0000x reference)
//
#include <hip/hip_runtime.h>

// PointWarping: B=2, C=3, N=8192. K=3 NN + inverse-distance flow interp.
// Round 12: ALGORITHMIC. Counting-sort candidates (warped x1+f1) and queries
// by x into 256 bins over [-6,6]; each wave serves 4 CDF-adjacent queries and
// expands a 64-candidate chunk window outward from the queries' x-position.
// A side stops when (dx_to_bin_edge)^2 > conservative-d3 for all 4 queries
// (d >= dx^2, so no unscanned candidate can improve; bin edges bound the
// within-bin disorder of counting sort; min-over-lanes k2 >= true d3 because
// each lane's own top-3 upper-bounds the union's). Exact direct-form packed
// keys (25-bit d | 7-bit chunk counter), keys-only butterfly, ballot index
// recovery via LDS chunk-base history, exact epilogue — all r7-validated.

#define NPTS   8192
#define BLOCK  256
#define QW     4                  // queries per wave
#define KMASK  0xFFFFFF80         // 25-bit distance | 7-bit chunk counter
#define MAXCH  128                // 128 chunks x 64 = whole array (guaranteed stop)
#define XLO    (-6.0f)
#define XW     (12.0f / 256.0f)
#define XINVW  (256.0f / 12.0f)
#define EPSV   1e-10f

__device__ __forceinline__ int xbin(float x) {
    int b = (int)floorf((x - XLO) * XINVW);
    return b < 0 ? 0 : (b > 255 ? 255 : b);
}

__device__ __forceinline__ float rfl_f32(float x) {
    return __int_as_float(__builtin_amdgcn_readfirstlane(__float_as_int(x)));
}

__device__ __forceinline__ void ksort3(float k, float& m0, float& m1, float& m2) {
    m2 = __builtin_amdgcn_fmed3f(k, m1, m2);
    m1 = __builtin_amdgcn_fmed3f(k, m0, m1);
    m0 = fminf(k, m0);
}

// ---- kernel 1: histograms of candidate-x and query-x (256 bins, per batch)
__global__ __launch_bounds__(256)
void hist_kernel(const float* __restrict__ xyz1, const float* __restrict__ flow1,
                 const float* __restrict__ xyz2, int* __restrict__ histC,
                 int* __restrict__ histQ) {
    const int i = blockIdx.x * 256 + threadIdx.x;      // 0..16383
    const int b = i >> 13, n = i & (NPTS - 1);
    const float px = xyz1[(size_t)b*3*NPTS + n] + flow1[(size_t)b*3*NPTS + n];
    atomicAdd(&histC[b*256 + xbin(px)], 1);
    const float qx = xyz2[(size_t)b*3*NPTS + n];
    atomicAdd(&histQ[b*256 + xbin(qx)], 1);
}

// ---- kernel 2: exclusive prefix sums (tiny, serial per array)
__global__ __launch_bounds__(64)
void prefix_kernel(const int* __restrict__ histC, const int* __restrict__ histQ,
                   int* __restrict__ pfC, int* __restrict__ ctrC,
                   int* __restrict__ ctrQ) {
    const int tid = threadIdx.x;
    if (tid < 2) {
        int s = 0;
        for (int k = 0; k < 256; ++k) {
            pfC[tid*256 + k] = s; ctrC[tid*256 + k] = s;
            s += histC[tid*256 + k];
        }
    } else if (tid < 4) {
        const int b = tid - 2;
        int s = 0;
        for (int k = 0; k < 256; ++k) {
            ctrQ[b*256 + k] = s;
            s += histQ[b*256 + k];
        }
    }
}

// ---- kernel 3: scatter into bin-sorted arrays
__global__ __launch_bounds__(256)
void scatter_kernel(const float* __restrict__ xyz1, const float* __restrict__ flow1,
                    const float* __restrict__ xyz2, int* __restrict__ ctrC,
                    int* __restrict__ ctrQ, float4* __restrict__ sortedC,
                    int* __restrict__ sortedQ) {
    const int i = blockIdx.x * 256 + threadIdx.x;
    const int b = i >> 13, n = i & (NPTS - 1);
    const float* x1 = xyz1 + (size_t)b * 3 * NPTS;
    const float* f1 = flow1 + (size_t)b * 3 * NPTS;
    const float px = x1[0*NPTS + n] + f1[0*NPTS + n];
    const float py = x1[1*NPTS + n] + f1[1*NPTS + n];
    const float pz = x1[2*NPTS + n] + f1[2*NPTS + n];
    const int pos = atomicAdd(&ctrC[b*256 + xbin(px)], 1);
    sortedC[(size_t)b*NPTS + pos] = make_float4(px, py, pz, __int_as_float(n));
    const float qx = xyz2[(size_t)b*3*NPTS + n];
    const int qpos = atomicAdd(&ctrQ[b*256 + xbin(qx)], 1);
    sortedQ[b*NPTS + qpos] = n;
}

// ---- kernel 4: windowed KNN + interp
__global__ __launch_bounds__(BLOCK, 8)
void knn_kernel(const float4* __restrict__ sortedC, const int* __restrict__ sortedQ,
                const int* __restrict__ pfC, const float* __restrict__ xyz2,
                const float* __restrict__ flow1, float* __restrict__ out) {
    __shared__ int s_cb[4][MAXCH];

    const int tid = threadIdx.x;
    const int w   = tid >> 6;
    const int t   = tid & 63;
    const int blocksPerB = (NPTS / (QW * 4));      // 512
    const int b = blockIdx.x / blocksPerB;
    const int g = (blockIdx.x % blocksPerB) * 4 + w;   // wave group [0,2048)

    const float4* sc = sortedC + (size_t)b * NPTS;
    const float*  x2 = xyz2 + (size_t)b * 3 * NPTS;
    const float*  f1 = flow1 + (size_t)b * 3 * NPTS;

    int   n2[QW];
    float qx[QW], qy[QW], qz[QW], k0[QW], k1[QW], k2[QW];
    #pragma unroll
    for (int i = 0; i < QW; ++i) {
        n2[i] = __builtin_amdgcn_readfirstlane(sortedQ[b*NPTS + g*QW + i]);
        qx[i] = rfl_f32(x2[0*NPTS + n2[i]]);
        qy[i] = rfl_f32(x2[1*NPTS + n2[i]]);
        qz[i] = rfl_f32(x2[2*NPTS + n2[i]]);
        k0[i] = k1[i] = k2[i] = 3e38f;
    }

    // window start: bin of query 0, back off 32, align 64
    int cb = pfC[b*256 + xbin(qx[0])] - 32;
    cb &= ~63;
    if (cb < 0) cb = 0;
    if (cb > NPTS - 64) cb = NPTS - 64;

    int L = cb, R = cb + 64, c = 0;

    // process chunk at base `cb` with counter `c`
    auto process = [&](int base, int cc) {
        const float4 p = sc[base + t];
        #pragma unroll
        for (int i = 0; i < QW; ++i) {
            const float dx = p.x - qx[i];
            const float dy = p.y - qy[i];
            const float dz = p.z - qz[i];
            const float d  = fmaf(dx, dx, fmaf(dy, dy, dz*dz));
            ksort3(__int_as_float((__float_as_int(d) & KMASK) | cc),
                   k0[i], k1[i], k2[i]);
        }
        s_cb[w][cc] = base;    // all lanes, same value
    };

    process(cb, 0);
    c = 1;
    bool doneL = (L == 0), doneR = (R >= NPTS);

    while ((!doneL || !doneR) && c < MAXCH) {
        // conservative d3 bound: min over lanes of each query's k2
        float km[QW];
        #pragma unroll
        for (int i = 0; i < QW; ++i) {
            float m = k2[i];
            #pragma unroll
            for (int step = 1; step < 64; step <<= 1)
                m = fminf(m, __shfl_xor(m, step, 64));
            km[i] = m;
        }
        float xlU = -1e30f, xrL = 1e30f;
        if (!doneL) {
            const float xl = sc[L-1].x;                       // uniform
            xlU = XLO + (float)(xbin(xl) + 1) * XW;           // upper bound of left region
            bool allq = true;
            #pragma unroll
            for (int i = 0; i < QW; ++i) {
                const float dl = qx[i] - xlU;
                if (!(dl > 0.0f && dl*dl > km[i])) allq = false;
            }
            doneL = allq;
        }
        if (!doneR) {
            const float xr = sc[R].x;
            xrL = XLO + (float)xbin(xr) * XW;                 // lower bound of right region
            bool allq = true;
            #pragma unroll
            for (int i = 0; i < QW; ++i) {
                const float dr = xrL - qx[i];
                if (!(dr > 0.0f && dr*dr > km[i])) allq = false;
            }
            doneR = allq;
        }
        if (doneL && doneR) break;
        const float xc = 0.25f * (qx[0] + qx[1] + qx[2] + qx[3]);
        bool goLeft;
        if (doneL)      goLeft = false;
        else if (doneR) goLeft = true;
        else            goLeft = (xc - xlU) <= (xrL - xc);
        if (goLeft) { L -= 64; process(L, c); doneL = (L == 0); }
        else        { process(R, c); R += 64; doneR = (R >= NPTS); }
        ++c;
    }

    // save pre-merge top-3 keys, then keys-only butterfly
    float a0[QW], a1[QW], a2[QW];
    #pragma unroll
    for (int i = 0; i < QW; ++i) { a0[i] = k0[i]; a1[i] = k1[i]; a2[i] = k2[i]; }
    #pragma unroll
    for (int step = 1; step < 64; step <<= 1) {
        #pragma unroll
        for (int i = 0; i < QW; ++i) {
            const float b0 = __shfl_xor(k0[i], step, 64);
            const float b1 = __shfl_xor(k1[i], step, 64);
            const float b2 = __shfl_xor(k2[i], step, 64);
            ksort3(b0, k0[i], k1[i], k2[i]);
            ksort3(b1, k0[i], k1[i], k2[i]);
            ksort3(b2, k0[i], k1[i], k2[i]);
        }
    }

    // resolve sorted-array positions: chunk base from history + lane from ballot
    int p0[QW], p1[QW], p2[QW];
    #pragma unroll
    for (int i = 0; i < QW; ++i) {
        {
            const float kf = k0[i];
            const unsigned long long m = __ballot(kf == a0[i] || kf == a1[i] || kf == a2[i]);
            p0[i] = s_cb[w][__float_as_int(kf) & 0x7F] + (__ffsll(m) - 1);
        }
        {
            const float kf = k1[i];
            const unsigned long long m = __ballot(kf == a0[i] || kf == a1[i] || kf == a2[i]);
            p1[i] = s_cb[w][__float_as_int(kf) & 0x7F] + (__ffsll(m) - 1);
        }
        {
            const float kf = k2[i];
            const unsigned long long m = __ballot(kf == a0[i] || kf == a1[i] || kf == a2[i]);
            p2[i] = s_cb[w][__float_as_int(kf) & 0x7F] + (__ffsll(m) - 1);
        }
    }

    // epilogue: lane i < QW handles query i — exact distances, weights, write
    if (t < QW) {
        const int i = t;
        const int ps[3] = {p0[i], p1[i], p2[i]};
        float dd[3]; int jj[3];
        #pragma unroll
        for (int s = 0; s < 3; ++s) {
            const float4 p = sc[ps[s]];
            jj[s] = __float_as_int(p.w);
            const float dx = p.x - qx[i], dy = p.y - qy[i], dz = p.z - qz[i];
            dd[s] = fmaf(dx, dx, fmaf(dy, dy, dz*dz));
        }
        float w0 = 1.0f / fmaxf(sqrtf(dd[0]), EPSV);
        float w1 = 1.0f / fmaxf(sqrtf(dd[1]), EPSV);
        float w2 = 1.0f / fmaxf(sqrtf(dd[2]), EPSV);
        const float ws = w0 + w1 + w2;
        w0 /= ws; w1 /= ws; w2 /= ws;

        float* o = out + (size_t)b * 3 * NPTS;
        #pragma unroll
        for (int ch = 0; ch < 3; ++ch) {
            const float fl = w0 * f1[ch*NPTS + jj[0]]
                           + w1 * f1[ch*NPTS + jj[1]]
                           + w2 * f1[ch*NPTS + jj[2]];
            o[ch*NPTS + n2[i]] = x2[ch*NPTS + n2[i]] - fl;
        }
    }
}

extern "C" void kernel_launch(void* const* d_in, const int* in_sizes, int n_in,
                              void* d_out, int out_size, void* d_ws, size_t ws_size,
                              hipStream_t stream) {
    const float* xyz1  = (const float*)d_in[0];
    const float* xyz2  = (const float*)d_in[1];
    const float* flow1 = (const float*)d_in[2];
    float* out = (float*)d_out;

    // ws layout
    float4* sortedC = (float4*)d_ws;                 // 2*8192*16 B
    int*    sortedQ = (int*)(sortedC + 2 * NPTS);    // 2*8192*4 B
    int*    histC   = sortedQ + 2 * NPTS;            // 512 ints
    int*    histQ   = histC + 512;                   // 512 ints
    int*    pfC     = histQ + 512;
    int*    ctrC    = pfC + 512;
    int*    ctrQ    = ctrC + 512;

    hipMemsetAsync(histC, 0, 1024 * sizeof(int), stream);   // histC+histQ
    hist_kernel<<<64, 256, 0, stream>>>(xyz1, flow1, xyz2, histC, histQ);
    prefix_kernel<<<1, 64, 0, stream>>>(histC, histQ, pfC, ctrC, ctrQ);
    scatter_kernel<<<64, 256, 0, stream>>>(xyz1, flow1, xyz2, ctrC, ctrQ,
                                           sortedC, sortedQ);
    knn_kernel<<<2 * (NPTS / (QW * 4)), BLOCK, 0, stream>>>(
        sortedC, sortedQ, pfC, xyz2, flow1, out);
}